// Round 13
// baseline (288.812 us; speedup 1.0000x reference)
//
#include <hip/hip_runtime.h>
#include <math.h>

// Round 19: R18 byte-identical except __launch_bounds__(256, 8).
// R18 landed at VGPR=68 — four registers over the 64-VGPR occupancy cliff
// (waves/SIMD halve at >64, m69), so occupancy stayed 25% despite the
// high-TLP geometry and VALUBusy 54%. The 2nd launch_bounds arg (min waves
// per EU) = 8 caps the allocator at 64 VGPR, forcing it to find 4 registers
// (remat or minor resched; worst case ~4-dword spill — tripwire WRITE_SIZE).
// LDS 18.9KB allows 8 blocks/CU, so LDS does not cap at 8 waves/SIMD.

#define LCH 512

struct Xf { float r[9]; float t[3]; };

__device__ __forceinline__ Xf xf_compose(const Xf& A, const Xf& B) {
  Xf C;
#pragma unroll
  for (int i = 0; i < 3; ++i) {
    float a0 = A.r[3*i+0], a1 = A.r[3*i+1], a2 = A.r[3*i+2];
    C.r[3*i+0] = a0*B.r[0] + a1*B.r[3] + a2*B.r[6];
    C.r[3*i+1] = a0*B.r[1] + a1*B.r[4] + a2*B.r[7];
    C.r[3*i+2] = a0*B.r[2] + a1*B.r[5] + a2*B.r[8];
    C.t[i]     = a0*B.t[0] + a1*B.t[1] + a2*B.t[2] + A.t[i];
  }
  return C;
}

// P := P o Delta(theta, len, tau), sparsity-aware (~31 FMA).
__device__ __forceinline__ void xf_step(Xf& P, float theta, float len, float tau) {
  float st, ct, sx, cx;
  __sincosf(theta, &st, &ct);
  __sincosf(tau, &sx, &cx);
  float ux = -ct, uy = cx*st, uz = sx*st;      // delta col0 (= d_local / L)
  float v0 = -st, v1 = -ct*cx, v2 = -ct*sx;    // delta col1; col2 = (0,-sx,cx)
  float c00 = P.r[0]*ux + P.r[1]*uy + P.r[2]*uz;
  float c10 = P.r[3]*ux + P.r[4]*uy + P.r[5]*uz;
  float c20 = P.r[6]*ux + P.r[7]*uy + P.r[8]*uz;
  float c01 = P.r[0]*v0 + P.r[1]*v1 + P.r[2]*v2;
  float c11 = P.r[3]*v0 + P.r[4]*v1 + P.r[5]*v2;
  float c21 = P.r[6]*v0 + P.r[7]*v1 + P.r[8]*v2;
  float c02 = P.r[2]*cx - P.r[1]*sx;
  float c12 = P.r[5]*cx - P.r[4]*sx;
  float c22 = P.r[8]*cx - P.r[7]*sx;
  P.t[0] += len*c00; P.t[1] += len*c10; P.t[2] += len*c20;
  P.r[0]=c00; P.r[1]=c01; P.r[2]=c02;
  P.r[3]=c10; P.r[4]=c11; P.r[5]=c12;
  P.r[6]=c20; P.r[7]=c21; P.r[8]=c22;
}

__device__ __forceinline__ void xf_set_delta(Xf& P, float theta, float len, float tau) {
  float st, ct, sx, cx;
  __sincosf(theta, &st, &ct);
  __sincosf(tau, &sx, &cx);
  float ux = -ct, uy = cx*st, uz = sx*st;
  P.r[0]=ux; P.r[1]=-st;    P.r[2]=0.f;
  P.r[3]=uy; P.r[4]=-ct*cx; P.r[5]=-sx;
  P.r[6]=uz; P.r[7]=-ct*sx; P.r[8]=cx;
  P.t[0]=len*ux; P.t[1]=len*uy; P.t[2]=len*uz;
}

__device__ __forceinline__ void xf_identity(Xf& A) {
  A.r[0]=1.f; A.r[1]=0.f; A.r[2]=0.f;
  A.r[3]=0.f; A.r[4]=1.f; A.r[5]=0.f;
  A.r[6]=0.f; A.r[7]=0.f; A.r[8]=1.f;
  A.t[0]=0.f; A.t[1]=0.f; A.t[2]=0.f;
}

__device__ __forceinline__ Xf xf_shfl_up(const Xf& P, int d) {
  Xf O;
#pragma unroll
  for (int i = 0; i < 9; ++i) O.r[i] = __shfl_up(P.r[i], d, 64);
#pragma unroll
  for (int i = 0; i < 3; ++i) O.t[i] = __shfl_up(P.t[i], d, 64);
  return O;
}

__global__ __launch_bounds__(256, 8) void nerf_r19_kernel(
    const float* __restrict__ g_phi, const float* __restrict__ g_psi,
    const float* __restrict__ g_omg, const float* __restrict__ g_bl,
    const float* __restrict__ g_ba, float* __restrict__ g_out)
{
  __shared__ float s_tot[36];           // wave 0..2 inclusive totals
  __shared__ float s_out[4608];         // linear output staging (18 KB)

  const int t    = threadIdx.x;         // 0..255
  const int lane = t & 63;
  const int wave = t >> 6;
  const int chain = blockIdx.x;

  const float* phir = g_phi + (size_t)chain * LCH;
  const float* psir = g_psi + (size_t)chain * LCH;
  const float* omgr = g_omg + (size_t)chain * LCH;
  const float* blr  = g_bl  + (size_t)chain * (LCH*3);
  const float* bar  = g_ba  + (size_t)chain * (LCH*3);

  const int j2 = 2 * t;                 // thread owns residues 2t-1, 2t
  const int b6 = 6 * t;

  // ---- 9 coalesced dwordx2 loads per thread ----
  float2 ps2 = *(const float2*)(psir + j2);      // psi[2t], psi[2t+1]
  float2 om2 = *(const float2*)(omgr + j2);
  float2 ph2 = *(const float2*)(phir + j2);      // phi[2t], phi[2t+1]
  float2 lb0 = *(const float2*)(blr + b6);       // bl[6t],   bl[6t+1]
  float2 lb1 = *(const float2*)(blr + b6 + 2);   // bl[6t+2], bl[6t+3]
  float2 lb2 = *(const float2*)(blr + b6 + 4);   // bl[6t+4], bl[6t+5]
  float2 ab0 = *(const float2*)(bar + b6);
  float2 ab1 = *(const float2*)(bar + b6 + 2);
  float2 ab2 = *(const float2*)(bar + b6 + 4);

  // ---- residue A (= 2t-1) params from neighbor's tail registers ----
  float psA  = __shfl_up(ps2.y, 1, 64);   // psi[2t-1]
  float omA  = __shfl_up(om2.y, 1, 64);   // omg[2t-1]
  float blA0 = __shfl_up(lb1.y, 1, 64);   // bl[6t-3]
  float blA1 = __shfl_up(lb2.x, 1, 64);   // bl[6t-2]
  float blA2 = __shfl_up(lb2.y, 1, 64);   // bl[6t-1]
  float baA0 = __shfl_up(ab1.y, 1, 64);
  float baA1 = __shfl_up(ab2.x, 1, 64);
  float baA2 = __shfl_up(ab2.y, 1, 64);
  if (lane == 0 && t != 0) {              // cross-wave edges (t=64,128,192)
    psA  = psir[j2 - 1];
    omA  = omgr[j2 - 1];
    blA0 = blr[b6 - 3]; blA1 = blr[b6 - 2]; blA2 = blr[b6 - 1];
    baA0 = bar[b6 - 3]; baA1 = bar[b6 - 2]; baA2 = bar[b6 - 1];
  }
  // (t==0: A params junk; chain A is identity-reset below)
  const float phA = ph2.x;                // phi[2t]   (tau of res 2t-1's C)
  // residue B (= 2t) params, all own registers:
  const float psB = ps2.x, omB = om2.x, phB = ph2.y;
  const float blB0 = lb0.x, blB1 = lb0.y, blB2 = lb1.x;
  const float baB0 = ab0.x, baB1 = ab0.y, baB2 = ab1.x;

  // ---- Phase A: two independent 3-step chains, interleaved (2x ILP) ----
  // residue j steps: N(theta=ba1,L=bl2,tau=psi) CA(ba2,bl0,omg) C(ba0,bl1,phi[j+1])
  Xf PA, PB;
  xf_set_delta(PA, baA1, blA2, psA);
  xf_set_delta(PB, baB1, blB2, psB);
  xf_step(PA, baA2, blA0, omA);
  xf_step(PB, baB2, blB0, omB);
  xf_step(PA, baA0, blA1, phA);
  xf_step(PB, baB0, blB1, phB);
  if (t == 0) xf_identity(PA);            // discard t=0 pre-roll chain
  Xf P = xf_compose(PA, PB);

  // ---- intra-wave inclusive scan (non-commutative), fully unrolled ----
#pragma unroll
  for (int d = 1; d < 64; d <<= 1) {
    Xf O = xf_shfl_up(P, d);
    if (lane >= d) P = xf_compose(O, P);
  }

  // waves 0..2 totals -> LDS
  if (lane == 63 && wave < 3) {
#pragma unroll
    for (int i = 0; i < 9; ++i) s_tot[12*wave + i] = P.r[i];
#pragma unroll
    for (int i = 0; i < 3; ++i) s_tot[12*wave + 9 + i] = P.t[i];
  }
  Xf E = xf_shfl_up(P, 1);   // within-wave exclusive (junk for lane 0)
  __syncthreads();

  // ---- prefix A = I0 [o T0][o T1][o T2] [o E] ----
  Xf A;
  A.r[0]=-0.849699f; A.r[1]=-0.223843f; A.r[2]=-0.477398f;
  A.r[3]=-0.019221f; A.r[4]= 0.917962f; A.r[5]=-0.396206f;
  A.r[6]= 0.526919f; A.r[7]=-0.327477f; A.r[8]=-0.784291f;
  A.t[0]=15.685f; A.t[1]=12.755f; A.t[2]=5.133f;
  if (wave >= 1) {
    Xf T;
#pragma unroll
    for (int i = 0; i < 9; ++i) T.r[i] = s_tot[i];
#pragma unroll
    for (int i = 0; i < 3; ++i) T.t[i] = s_tot[9+i];
    A = xf_compose(A, T);
  }
  if (wave >= 2) {
    Xf T;
#pragma unroll
    for (int i = 0; i < 9; ++i) T.r[i] = s_tot[12+i];
#pragma unroll
    for (int i = 0; i < 3; ++i) T.t[i] = s_tot[21+i];
    A = xf_compose(A, T);
  }
  if (wave >= 3) {
    Xf T;
#pragma unroll
    for (int i = 0; i < 9; ++i) T.r[i] = s_tot[24+i];
#pragma unroll
    for (int i = 0; i < 3; ++i) T.t[i] = s_tot[33+i];
    A = xf_compose(A, T);
  }
  if (lane > 0) A = xf_compose(A, E);

  // ---- replay by recompute: 6 serial steps from A, stage into LDS ----
  float* o = s_out + 18 * t;
  if (t == 0) {
    o[0]=17.047f; o[1]=14.099f; o[2]=3.625f;
    o[3]=16.967f; o[4]=12.784f; o[5]=4.338f;
    o[6]=15.685f; o[7]=12.755f; o[8]=5.133f;
  } else {
    xf_step(A, baA1, blA2, psA);
    o[0]=A.t[0]; o[1]=A.t[1]; o[2]=A.t[2];
    xf_step(A, baA2, blA0, omA);
    o[3]=A.t[0]; o[4]=A.t[1]; o[5]=A.t[2];
    xf_step(A, baA0, blA1, phA);
    o[6]=A.t[0]; o[7]=A.t[1]; o[8]=A.t[2];
  }
  xf_step(A, baB1, blB2, psB);
  o[9]=A.t[0];  o[10]=A.t[1]; o[11]=A.t[2];
  xf_step(A, baB2, blB0, omB);
  o[12]=A.t[0]; o[13]=A.t[1]; o[14]=A.t[2];
  xf_step(A, baB0, blB1, phB);
  o[15]=A.t[0]; o[16]=A.t[1]; o[17]=A.t[2];
  __syncthreads();

  // ---- coalesced float2 sweep (512B contiguous per wave round) ----
  float* orow = g_out + (size_t)chain * 4608;
#pragma unroll
  for (int q = 0; q < 9; ++q) {
    const int g = 2*t + 512*q;
    float2 v = *(const float2*)(s_out + g);
    *(float2*)(orow + g) = v;
  }
}

extern "C" void kernel_launch(void* const* d_in, const int* in_sizes, int n_in,
                              void* d_out, int out_size, void* d_ws, size_t ws_size,
                              hipStream_t stream) {
  const float* phi = (const float*)d_in[0];
  const float* psi = (const float*)d_in[1];
  const float* omg = (const float*)d_in[2];
  const float* bl  = (const float*)d_in[3];
  const float* ba  = (const float*)d_in[4];
  float* out = (float*)d_out;
  const int B = in_sizes[0] / LCH;          // 4096 chains
  hipLaunchKernelGGL(nerf_r19_kernel, dim3(B), dim3(256), 0, stream,
                     phi, psi, omg, bl, ba, out);
}

// Round 14
// 146.246 us; speedup vs baseline: 1.9748x; 1.9748x over previous
//
#include <hip/hip_runtime.h>
#include <math.h>

// Round 20: earn 4 VGPRs instead of forcing them (R19: forced cap -> 32 VGPR
// quantum + catastrophic spill, 194us). R18 structure (natural 68 VGPR,
// VALUBusy 54%) with two surgical pressure reductions at the post-scan peak:
//  1. Cumulative wave prefixes precomputed in LDS by thread 0 (2 composes,
//     negligible) -> each wave does ONE T-compose instead of up to 3.
//  2. The wave prefix is wave-uniform -> readfirstlane its 12 floats into
//     SGPRs before the compose (FMA reads 1 SGPR operand: legal) -> -12 VGPR
//     at peak liveness.
// Target: natural allocation <= 64 VGPR (8 waves/SIMD). Tripwires:
// VGPR_Count <= 64, WRITE_SIZE == 73728 KB exactly.

#define LCH 512

struct Xf { float r[9]; float t[3]; };

__device__ __forceinline__ Xf xf_compose(const Xf& A, const Xf& B) {
  Xf C;
#pragma unroll
  for (int i = 0; i < 3; ++i) {
    float a0 = A.r[3*i+0], a1 = A.r[3*i+1], a2 = A.r[3*i+2];
    C.r[3*i+0] = a0*B.r[0] + a1*B.r[3] + a2*B.r[6];
    C.r[3*i+1] = a0*B.r[1] + a1*B.r[4] + a2*B.r[7];
    C.r[3*i+2] = a0*B.r[2] + a1*B.r[5] + a2*B.r[8];
    C.t[i]     = a0*B.t[0] + a1*B.t[1] + a2*B.t[2] + A.t[i];
  }
  return C;
}

// P := P o Delta(theta, len, tau), sparsity-aware (~31 FMA).
__device__ __forceinline__ void xf_step(Xf& P, float theta, float len, float tau) {
  float st, ct, sx, cx;
  __sincosf(theta, &st, &ct);
  __sincosf(tau, &sx, &cx);
  float ux = -ct, uy = cx*st, uz = sx*st;      // delta col0 (= d_local / L)
  float v0 = -st, v1 = -ct*cx, v2 = -ct*sx;    // delta col1; col2 = (0,-sx,cx)
  float c00 = P.r[0]*ux + P.r[1]*uy + P.r[2]*uz;
  float c10 = P.r[3]*ux + P.r[4]*uy + P.r[5]*uz;
  float c20 = P.r[6]*ux + P.r[7]*uy + P.r[8]*uz;
  float c01 = P.r[0]*v0 + P.r[1]*v1 + P.r[2]*v2;
  float c11 = P.r[3]*v0 + P.r[4]*v1 + P.r[5]*v2;
  float c21 = P.r[6]*v0 + P.r[7]*v1 + P.r[8]*v2;
  float c02 = P.r[2]*cx - P.r[1]*sx;
  float c12 = P.r[5]*cx - P.r[4]*sx;
  float c22 = P.r[8]*cx - P.r[7]*sx;
  P.t[0] += len*c00; P.t[1] += len*c10; P.t[2] += len*c20;
  P.r[0]=c00; P.r[1]=c01; P.r[2]=c02;
  P.r[3]=c10; P.r[4]=c11; P.r[5]=c12;
  P.r[6]=c20; P.r[7]=c21; P.r[8]=c22;
}

__device__ __forceinline__ void xf_set_delta(Xf& P, float theta, float len, float tau) {
  float st, ct, sx, cx;
  __sincosf(theta, &st, &ct);
  __sincosf(tau, &sx, &cx);
  float ux = -ct, uy = cx*st, uz = sx*st;
  P.r[0]=ux; P.r[1]=-st;    P.r[2]=0.f;
  P.r[3]=uy; P.r[4]=-ct*cx; P.r[5]=-sx;
  P.r[6]=uz; P.r[7]=-ct*sx; P.r[8]=cx;
  P.t[0]=len*ux; P.t[1]=len*uy; P.t[2]=len*uz;
}

__device__ __forceinline__ void xf_identity(Xf& A) {
  A.r[0]=1.f; A.r[1]=0.f; A.r[2]=0.f;
  A.r[3]=0.f; A.r[4]=1.f; A.r[5]=0.f;
  A.r[6]=0.f; A.r[7]=0.f; A.r[8]=1.f;
  A.t[0]=0.f; A.t[1]=0.f; A.t[2]=0.f;
}

__device__ __forceinline__ Xf xf_shfl_up(const Xf& P, int d) {
  Xf O;
#pragma unroll
  for (int i = 0; i < 9; ++i) O.r[i] = __shfl_up(P.r[i], d, 64);
#pragma unroll
  for (int i = 0; i < 3; ++i) O.t[i] = __shfl_up(P.t[i], d, 64);
  return O;
}

__device__ __forceinline__ float rfl(float x) {
  return __int_as_float(__builtin_amdgcn_readfirstlane(__float_as_int(x)));
}

__global__ __launch_bounds__(256) void nerf_r20_kernel(
    const float* __restrict__ g_phi, const float* __restrict__ g_psi,
    const float* __restrict__ g_omg, const float* __restrict__ g_bl,
    const float* __restrict__ g_ba, float* __restrict__ g_out)
{
  __shared__ float s_tot[36];           // cumulative wave prefixes C1,C2,C3
  __shared__ float s_out[4608];         // linear output staging (18 KB)

  const int t    = threadIdx.x;         // 0..255
  const int lane = t & 63;
  const int wave = t >> 6;
  const int chain = blockIdx.x;

  const float* phir = g_phi + (size_t)chain * LCH;
  const float* psir = g_psi + (size_t)chain * LCH;
  const float* omgr = g_omg + (size_t)chain * LCH;
  const float* blr  = g_bl  + (size_t)chain * (LCH*3);
  const float* bar  = g_ba  + (size_t)chain * (LCH*3);

  const int j2 = 2 * t;                 // thread owns residues 2t-1, 2t
  const int b6 = 6 * t;

  // ---- 9 coalesced dwordx2 loads per thread ----
  float2 ps2 = *(const float2*)(psir + j2);      // psi[2t], psi[2t+1]
  float2 om2 = *(const float2*)(omgr + j2);
  float2 ph2 = *(const float2*)(phir + j2);      // phi[2t], phi[2t+1]
  float2 lb0 = *(const float2*)(blr + b6);       // bl[6t],   bl[6t+1]
  float2 lb1 = *(const float2*)(blr + b6 + 2);   // bl[6t+2], bl[6t+3]
  float2 lb2 = *(const float2*)(blr + b6 + 4);   // bl[6t+4], bl[6t+5]
  float2 ab0 = *(const float2*)(bar + b6);
  float2 ab1 = *(const float2*)(bar + b6 + 2);
  float2 ab2 = *(const float2*)(bar + b6 + 4);

  // ---- residue A (= 2t-1) params from neighbor's tail registers ----
  float psA  = __shfl_up(ps2.y, 1, 64);   // psi[2t-1]
  float omA  = __shfl_up(om2.y, 1, 64);   // omg[2t-1]
  float blA0 = __shfl_up(lb1.y, 1, 64);   // bl[6t-3]
  float blA1 = __shfl_up(lb2.x, 1, 64);   // bl[6t-2]
  float blA2 = __shfl_up(lb2.y, 1, 64);   // bl[6t-1]
  float baA0 = __shfl_up(ab1.y, 1, 64);
  float baA1 = __shfl_up(ab2.x, 1, 64);
  float baA2 = __shfl_up(ab2.y, 1, 64);
  if (lane == 0 && t != 0) {              // cross-wave edges (t=64,128,192)
    psA  = psir[j2 - 1];
    omA  = omgr[j2 - 1];
    blA0 = blr[b6 - 3]; blA1 = blr[b6 - 2]; blA2 = blr[b6 - 1];
    baA0 = bar[b6 - 3]; baA1 = bar[b6 - 2]; baA2 = bar[b6 - 1];
  }
  // (t==0: A params junk; chain A is identity-reset below)
  const float phA = ph2.x;                // phi[2t]   (tau of res 2t-1's C)
  // residue B (= 2t) params, all own registers:
  const float psB = ps2.x, omB = om2.x, phB = ph2.y;
  const float blB0 = lb0.x, blB1 = lb0.y, blB2 = lb1.x;
  const float baB0 = ab0.x, baB1 = ab0.y, baB2 = ab1.x;

  // ---- Phase A: two independent 3-step chains, interleaved (2x ILP) ----
  // residue j steps: N(theta=ba1,L=bl2,tau=psi) CA(ba2,bl0,omg) C(ba0,bl1,phi[j+1])
  Xf PA, PB;
  xf_set_delta(PA, baA1, blA2, psA);
  xf_set_delta(PB, baB1, blB2, psB);
  xf_step(PA, baA2, blA0, omA);
  xf_step(PB, baB2, blB0, omB);
  xf_step(PA, baA0, blA1, phA);
  xf_step(PB, baB0, blB1, phB);
  if (t == 0) xf_identity(PA);            // discard t=0 pre-roll chain
  Xf P = xf_compose(PA, PB);

  // ---- intra-wave inclusive scan (non-commutative), fully unrolled ----
#pragma unroll
  for (int d = 1; d < 64; d <<= 1) {
    Xf O = xf_shfl_up(P, d);
    if (lane >= d) P = xf_compose(O, P);
  }

  // waves 0..2 totals -> LDS (raw; cumulated by thread 0 below)
  if (lane == 63 && wave < 3) {
#pragma unroll
    for (int i = 0; i < 9; ++i) s_tot[12*wave + i] = P.r[i];
#pragma unroll
    for (int i = 0; i < 3; ++i) s_tot[12*wave + 9 + i] = P.t[i];
  }
  Xf E = xf_shfl_up(P, 1);   // within-wave exclusive (junk for lane 0)
  __syncthreads();

  // ---- thread 0: cumulate wave prefixes in LDS ----
  // C1 = T0 (already at 0..11); C2 = T0 o T1 -> 12..23; C3 = C2 o T2 -> 24..35
  if (t == 0) {
    Xf T0, T1, T2;
#pragma unroll
    for (int i = 0; i < 9; ++i) { T0.r[i]=s_tot[i]; T1.r[i]=s_tot[12+i]; T2.r[i]=s_tot[24+i]; }
#pragma unroll
    for (int i = 0; i < 3; ++i) { T0.t[i]=s_tot[9+i]; T1.t[i]=s_tot[21+i]; T2.t[i]=s_tot[33+i]; }
    Xf C2 = xf_compose(T0, T1);
    Xf C3 = xf_compose(C2, T2);
#pragma unroll
    for (int i = 0; i < 9; ++i) { s_tot[12+i] = C2.r[i]; s_tot[24+i] = C3.r[i]; }
#pragma unroll
    for (int i = 0; i < 3; ++i) { s_tot[21+i] = C2.t[i]; s_tot[33+i] = C3.t[i]; }
  }
  __syncthreads();

  // ---- prefix A = I0 [o C_wave] [o E] ----
  Xf A;
  A.r[0]=-0.849699f; A.r[1]=-0.223843f; A.r[2]=-0.477398f;
  A.r[3]=-0.019221f; A.r[4]= 0.917962f; A.r[5]=-0.396206f;
  A.r[6]= 0.526919f; A.r[7]=-0.327477f; A.r[8]=-0.784291f;
  A.t[0]=15.685f; A.t[1]=12.755f; A.t[2]=5.133f;
  if (wave >= 1) {
    const int o = 12 * (wave - 1);
    Xf T;   // wave-uniform -> SGPRs via readfirstlane
#pragma unroll
    for (int i = 0; i < 9; ++i) T.r[i] = rfl(s_tot[o + i]);
#pragma unroll
    for (int i = 0; i < 3; ++i) T.t[i] = rfl(s_tot[o + 9 + i]);
    A = xf_compose(A, T);
  }
  if (lane > 0) A = xf_compose(A, E);

  // ---- replay by recompute: 6 serial steps from A, stage into LDS ----
  float* o = s_out + 18 * t;
  if (t == 0) {
    o[0]=17.047f; o[1]=14.099f; o[2]=3.625f;
    o[3]=16.967f; o[4]=12.784f; o[5]=4.338f;
    o[6]=15.685f; o[7]=12.755f; o[8]=5.133f;
  } else {
    xf_step(A, baA1, blA2, psA);
    o[0]=A.t[0]; o[1]=A.t[1]; o[2]=A.t[2];
    xf_step(A, baA2, blA0, omA);
    o[3]=A.t[0]; o[4]=A.t[1]; o[5]=A.t[2];
    xf_step(A, baA0, blA1, phA);
    o[6]=A.t[0]; o[7]=A.t[1]; o[8]=A.t[2];
  }
  xf_step(A, baB1, blB2, psB);
  o[9]=A.t[0];  o[10]=A.t[1]; o[11]=A.t[2];
  xf_step(A, baB2, blB0, omB);
  o[12]=A.t[0]; o[13]=A.t[1]; o[14]=A.t[2];
  xf_step(A, baB0, blB1, phB);
  o[15]=A.t[0]; o[16]=A.t[1]; o[17]=A.t[2];
  __syncthreads();

  // ---- coalesced float2 sweep (512B contiguous per wave round) ----
  float* orow = g_out + (size_t)chain * 4608;
#pragma unroll
  for (int q = 0; q < 9; ++q) {
    const int g = 2*t + 512*q;
    float2 v = *(const float2*)(s_out + g);
    *(float2*)(orow + g) = v;
  }
}

extern "C" void kernel_launch(void* const* d_in, const int* in_sizes, int n_in,
                              void* d_out, int out_size, void* d_ws, size_t ws_size,
                              hipStream_t stream) {
  const float* phi = (const float*)d_in[0];
  const float* psi = (const float*)d_in[1];
  const float* omg = (const float*)d_in[2];
  const float* bl  = (const float*)d_in[3];
  const float* ba  = (const float*)d_in[4];
  float* out = (float*)d_out;
  const int B = in_sizes[0] / LCH;          // 4096 chains
  hipLaunchKernelGGL(nerf_r20_kernel, dim3(B), dim3(256), 0, stream,
                     phi, psi, omg, bl, ba, out);
}